// Round 8
// baseline (227.693 us; speedup 1.0000x reference)
//
#include <hip/hip_runtime.h>
#include <stdint.h>

#define BATCH 16
#define NDET 25200
#define NCLS 80
#define PREDC 85
#define KTOP 2048
#define MAXDET 300
#define OUTC 86
#define CONF_THR 0.4f
#define IOU_THR 0.45f
#define MAXWH 4096.0f
#define MROWS (KTOP + 64)       // padded mask rows per batch
#define NBIN 2048
#define NREP 4
#define INVHI 0xBF800000u       // ~mono(-1.0f): score word of invalid rows
#define BMW (NCLS * 64)         // class bitmap words per batch (80 classes x 64)

#define REP32(F) F(0)F(1)F(2)F(3)F(4)F(5)F(6)F(7)F(8)F(9)F(10)F(11)F(12)F(13)F(14)F(15)F(16)F(17)F(18)F(19)F(20)F(21)F(22)F(23)F(24)F(25)F(26)F(27)F(28)F(29)F(30)F(31)

// ---- monotone float<->uint mapping (ascending) ----
__device__ __forceinline__ uint32_t mono_f32(float f) {
  uint32_t u = __float_as_uint(f);
  return (u & 0x80000000u) ? ~u : (u | 0x80000000u);
}
__device__ __forceinline__ float unmono_f32(uint32_t m) {
  uint32_t u = (m & 0x80000000u) ? (m & 0x7FFFFFFFu) : ~m;
  return __uint_as_float(u);
}

// K1: per-candidate score/class -> packed 64-bit key + 32-bit score word.
__global__ void k_keys(const float* __restrict__ pred, uint64_t* __restrict__ keys,
                       uint32_t* __restrict__ sw) {
  int idx = blockIdx.x * blockDim.x + threadIdx.x;
  if (idx >= BATCH * NDET) return;
  int n = idx % NDET;
  const float* p = pred + (size_t)idx * PREDC;
  float obj = p[4];
  float score = -1.0f;
  uint32_t cls = 0;
  if (obj > CONF_THR) {
    float best = -1e30f;
    int bc = 0;
    for (int c = 0; c < NCLS; ++c) {
      float s = __fmul_rn(p[5 + c], obj);   // single-rounded, no contraction
      if (s > best) { best = s; bc = c; }   // strict > : first max (argmax)
    }
    if (best > CONF_THR) { score = best; cls = (uint32_t)bc; }
  }
  uint32_t hi = ~mono_f32(score);
  sw[idx] = hi;
  keys[idx] = ((uint64_t)hi << 32) | (uint64_t)(((uint32_t)n << 7) | cls);
}

// K2: fused radix-select (3x11-bit on score word, exact tie refine) + collect +
// bitonic sort + derive (+ integer class array + per-class rank bitmap).
// One 1024-thread block per batch.
__global__ void __launch_bounds__(1024) k_sel(
    const uint64_t* __restrict__ keys, const uint32_t* __restrict__ sw,
    const float* __restrict__ pred,
    uint32_t* __restrict__ s_n, float* __restrict__ s_score, float* __restrict__ s_clsf,
    uint32_t* __restrict__ s_cli, uint32_t* __restrict__ clsbm,
    float* __restrict__ s_box, float* __restrict__ s_obox, uint32_t* __restrict__ nvalid) {
  __shared__ uint64_t sk[KTOP];            // 16 KB
  __shared__ uint32_t hist[NREP][NBIN];    // 32 KB (reused as class bitmap later)
  __shared__ uint32_t seg[32];
  __shared__ uint32_t sh_digit, sh_cnt, sh_k;
  __shared__ uint32_t ncol, nv;
  int b = blockIdx.x, tid = threadIdx.x, lane = tid & 63;
  int rep = (tid >> 8) & (NREP - 1);
  const uint64_t* kb = keys + (size_t)b * NDET;
  const uint32_t* swb = sw + (size_t)b * NDET;
  const uint4* sw4 = (const uint4*)swb;
  if (tid == 0) { sh_k = KTOP; ncol = 0; nv = 0; }

#define CLEAR_HIST() { __syncthreads(); \
  for (int i = tid; i < NREP * NBIN; i += 1024) ((uint32_t*)hist)[i] = 0; \
  __syncthreads(); }

#define FIND() { __syncthreads(); \
  for (int t = tid; t < NBIN; t += 1024) \
    hist[0][t] = hist[0][t] + hist[1][t] + hist[2][t] + hist[3][t]; \
  __syncthreads(); \
  if (tid < 32) { uint32_t s_ = 0; \
    for (int i_ = 0; i_ < 64; ++i_) s_ += hist[0][tid * 64 + i_]; \
    seg[tid] = s_; } \
  __syncthreads(); \
  if (tid == 0) { uint32_t k_ = sh_k, cum_ = 0; int S_ = 0; \
    for (; S_ < 31; ++S_) { if (cum_ + seg[S_] >= k_) break; cum_ += seg[S_]; } \
    int d_ = S_ * 64; \
    for (;; ++d_) { if (cum_ + hist[0][d_] >= k_) break; cum_ += hist[0][d_]; } \
    sh_digit = (uint32_t)d_; sh_cnt = hist[0][d_]; sh_k = k_ - cum_; } \
  __syncthreads(); }

  // ---- pass 0: bits [31:21] ----
  CLEAR_HIST();
  {
    uint32_t invc = 0;
#define P0(s) { if ((s) == INVHI) ++invc; else atomicAdd(&hist[rep][(s) >> 21], 1u); }
    for (int i = tid; i < NDET / 4; i += 1024) {
      uint4 v = sw4[i];
      P0(v.x) P0(v.y) P0(v.z) P0(v.w)
    }
    if (invc) atomicAdd(&hist[rep][INVHI >> 21], invc);
  }
  FIND();
  uint32_t d0 = sh_digit;

  // ---- pass 1: bits [20:10] among prefix d0 ----
  CLEAR_HIST();
  {
    uint32_t invc = 0;
#define P1(s) { if ((s) == INVHI) ++invc; \
    else if (((s) >> 21) == d0) atomicAdd(&hist[rep][((s) >> 10) & 0x7FFu], 1u); }
    for (int i = tid; i < NDET / 4; i += 1024) {
      uint4 v = sw4[i];
      P1(v.x) P1(v.y) P1(v.z) P1(v.w)
    }
    if (invc && (INVHI >> 21) == d0) atomicAdd(&hist[rep][(INVHI >> 10) & 0x7FFu], invc);
  }
  FIND();
  uint32_t pref21 = (d0 << 11) | sh_digit;

  // ---- pass 2: bits [9:0] among prefix ----
  CLEAR_HIST();
  {
    uint32_t invc = 0;
#define P2(s) { if ((s) == INVHI) ++invc; \
    else if (((s) >> 10) == pref21) atomicAdd(&hist[rep][(s) & 0x3FFu], 1u); }
    for (int i = tid; i < NDET / 4; i += 1024) {
      uint4 v = sw4[i];
      P2(v.x) P2(v.y) P2(v.z) P2(v.w)
    }
    if (invc && (INVHI >> 10) == pref21) atomicAdd(&hist[rep][INVHI & 0x3FFu], invc);
  }
  FIND();
  uint32_t sstar = (pref21 << 10) | sh_digit;
  uint32_t E = sh_cnt, r = sh_k;           // 1 <= r <= E
  uint32_t Lstar = 0xFFFFFFFFu;

  if (r < E) {
    // exact tie refine: r-th smallest low word (22 bits) among sw==sstar.
    CLEAR_HIST();
    for (int n = tid; n < NDET; n += 1024) {
      uint64_t key = kb[n];
      if ((uint32_t)(key >> 32) == sstar)
        atomicAdd(&hist[rep][((uint32_t)key >> 11) & 0x7FFu], 1u);
    }
    FIND();
    uint32_t dr0 = sh_digit;
    CLEAR_HIST();
    for (int n = tid; n < NDET; n += 1024) {
      uint64_t key = kb[n];
      uint32_t low = (uint32_t)key;
      if ((uint32_t)(key >> 32) == sstar && ((low >> 11) & 0x7FFu) == dr0)
        atomicAdd(&hist[rep][low & 0x7FFu], 1u);
    }
    FIND();
    Lstar = (dr0 << 11) | sh_digit;
  }

  // ---- collect exactly KTOP keys ----
  for (int n = tid; n < NDET; n += 1024) {
    uint64_t key = kb[n];
    uint32_t hi = (uint32_t)(key >> 32);
    bool inc = (hi < sstar) || (hi == sstar && (uint32_t)key <= Lstar);
    uint64_t ball = __ballot(inc);
    uint32_t bse = 0;
    if (lane == 0) bse = atomicAdd(&ncol, (uint32_t)__popcll(ball));
    bse = __shfl(bse, 0);
    if (inc) {
      uint32_t pos = bse + (uint32_t)__popcll(ball & ((1ull << lane) - 1ull));
      if (pos < KTOP) sk[pos] = key;
    }
  }

  // ---- bitonic sort ascending ----
  for (int kk = 2; kk <= KTOP; kk <<= 1) {
    for (int j = kk >> 1; j > 0; j >>= 1) {
      __syncthreads();
      for (int i = tid; i < KTOP; i += 1024) {
        int ixj = i ^ j;
        if (ixj > i) {
          uint64_t a = sk[i], c = sk[ixj];
          bool asc = ((i & kk) == 0);
          if ((a > c) == asc) { sk[i] = c; sk[ixj] = a; }
        }
      }
    }
  }
  __syncthreads();

  // ---- class bitmap (reuse hist space; all hist uses are done) ----
  uint32_t* bm = (uint32_t*)hist;          // BMW = 5120 words <= 8192
  for (int i = tid; i < BMW; i += 1024) bm[i] = 0;
  __syncthreads();

  // ---- derive arrays ----
  for (int rr = tid; rr < KTOP; rr += 1024) {
    uint64_t key = sk[rr];
    float score = unmono_f32(~(uint32_t)(key >> 32));
    uint32_t low = (uint32_t)key;
    uint32_t n = low >> 7;
    uint32_t cls = low & 127u;
    uint64_t vball = __ballot(score > 0.0f);
    if (lane == 0) atomicAdd(&nv, (uint32_t)__popcll(vball));
    if (score > 0.0f) atomicOr(&bm[cls * 64 + (rr >> 5)], 1u << (rr & 31));
    const float* p = pred + ((size_t)b * NDET + n) * PREDC;
    float x = p[0], y = p[1], w = p[2], h = p[3];
    float hw = __fmul_rn(w, 0.5f), hh = __fmul_rn(h, 0.5f);
    float x1 = __fsub_rn(x, hw), y1 = __fsub_rn(y, hh);
    float x2 = __fadd_rn(x, hw), y2 = __fadd_rn(y, hh);
    float clsf = (float)cls;
    float off = __fmul_rn(clsf, MAXWH);
    size_t o = (size_t)b * KTOP + rr;
    s_n[o] = n;
    s_score[o] = score;
    s_clsf[o] = clsf;
    s_cli[o] = cls;
    s_box[o * 4 + 0] = x1; s_box[o * 4 + 1] = y1;
    s_box[o * 4 + 2] = x2; s_box[o * 4 + 3] = y2;
    s_obox[o * 4 + 0] = __fadd_rn(x1, off); s_obox[o * 4 + 1] = __fadd_rn(y1, off);
    s_obox[o * 4 + 2] = __fadd_rn(x2, off); s_obox[o * 4 + 3] = __fadd_rn(y2, off);
  }
  __syncthreads();
  for (int i = tid; i < BMW; i += 1024) clsbm[(size_t)b * BMW + i] = bm[i];
  if (tid == 0) nvalid[b] = nv;
}

// K5: suppression bitmask via per-class rank bitmap (cross-class IoU == 0 exactly).
__global__ void k_mask(const float* __restrict__ s_obox, const uint32_t* __restrict__ s_cli,
                       const uint32_t* __restrict__ clsbm, const uint32_t* __restrict__ nvalid,
                       uint32_t* __restrict__ mask, uint32_t* __restrict__ diag) {
  int gid = blockIdx.x * blockDim.x + threadIdx.x; // BATCH*KTOP*64 threads
  int w = gid & 63;
  int i = (gid >> 6) & (KTOP - 1);
  int b = gid >> 17;
  if (i >= (int)nvalid[b]) return;
  int iw = i >> 5, ib = i & 31;
  uint32_t word = 0;
  if (w >= iw) {
    uint32_t ci = s_cli[(size_t)b * KTOP + i];
    uint32_t bmw = clsbm[(size_t)b * BMW + ci * 64 + w];
    uint32_t uptri = (w > iw) ? 0xFFFFFFFFu : ((ib == 31) ? 0u : (0xFFFFFFFFu << (ib + 1)));
    uint32_t mbits = bmw & uptri;
    if (mbits) {
      const float* bi = s_obox + ((size_t)b * KTOP + i) * 4;
      float ix1 = bi[0], iy1 = bi[1], ix2 = bi[2], iy2 = bi[3];
      float iarea = __fmul_rn(__fsub_rn(ix2, ix1), __fsub_rn(iy2, iy1));
      int j0 = w * 32;
      do {
        int t = __ffs(mbits) - 1;
        mbits &= mbits - 1;
        int j = j0 + t;
        const float* bj = s_obox + ((size_t)b * KTOP + j) * 4;
        float jx1 = bj[0], jy1 = bj[1], jx2 = bj[2], jy2 = bj[3];
        float jarea = __fmul_rn(__fsub_rn(jx2, jx1), __fsub_rn(jy2, jy1));
        float ltx = fmaxf(ix1, jx1), lty = fmaxf(iy1, jy1);
        float rbx = fminf(ix2, jx2), rby = fminf(iy2, jy2);
        float wx = fmaxf(__fsub_rn(rbx, ltx), 0.0f);
        float wy = fmaxf(__fsub_rn(rby, lty), 0.0f);
        float inter = __fmul_rn(wx, wy);
        float denom = __fadd_rn(__fsub_rn(__fadd_rn(iarea, jarea), inter), 1e-7f);
        float iou = __fdiv_rn(inter, denom);
        if (iou > IOU_THR) word |= (1u << t);
      } while (mbits);
    }
  }
  mask[((size_t)b * MROWS + i) * 64 + w] = word;
  if (w == iw) diag[(size_t)b * KTOP + i] = word;
}

// K6: sequential greedy pass, one wave per batch; lane l owns removed word l.
__global__ void __launch_bounds__(64, 1) k_nms(
    const uint32_t* __restrict__ mask, const uint32_t* __restrict__ diag,
    const uint32_t* __restrict__ nvalid, uint32_t* __restrict__ supp) {
  __shared__ uint32_t ldsd[KTOP];
  int b = blockIdx.x;
  int lane = threadIdx.x; // 64 threads = 1 wave
  int nv = (int)nvalid[b];
  const uint32_t* mbl = mask + (size_t)b * MROWS * 64 + lane;
  const uint32_t* db = diag + (size_t)b * KTOP;
  for (int i = lane; i < KTOP; i += 64) ldsd[i] = db[i];
  __syncthreads();
  uint32_t removed = 0;
  int ngrp = (nv + 31) >> 5;
  for (int g = 0; g < ngrp; ++g) {
    int base = g * 32;
    int rem = nv - base;
    uint32_t vm = (rem >= 32) ? 0xFFFFFFFFu : ((1u << rem) - 1u);
    const uint32_t* rp = mbl + (size_t)base * 64;
#define DECL_R(d) uint32_t R##d = rp[(size_t)(d) * 64];
    REP32(DECL_R)
#define PIN_R(d) asm volatile("" : "+v"(R##d));
    REP32(PIN_R)
#define DECL_S(d) uint32_t S##d = ldsd[base + d] & ((uint32_t)0 - ((vm >> d) & 1u));
    REP32(DECL_S)
    uint32_t curw = __shfl(removed, g);
    uint32_t cinit = curw;
#define CHAIN(d) { uint32_t m_ = ((curw >> d) & 1u) - 1u; curw |= m_ & S##d; }
    REP32(CHAIN)
    uint32_t am = vm & ~(curw | cinit);
#define APPLY(d) removed |= R##d & ((uint32_t)0 - ((am >> d) & 1u));
    REP32(APPLY)
  }
  supp[b * 64 + lane] = removed;
}

// K7: write the ENTIRE output (data rows + zero rows) — replaces hipMemsetAsync,
// whose rocclr fill kernel ran at 21 GB/s and cost 78 us in the timed graph.
__global__ void __launch_bounds__(256) k_out(
    const uint32_t* __restrict__ supp, const uint32_t* __restrict__ nvalid,
    const uint32_t* __restrict__ s_n, const float* __restrict__ s_score,
    const float* __restrict__ s_clsf, const float* __restrict__ s_box,
    const float* __restrict__ logits, float* __restrict__ out) {
  __shared__ uint32_t keepw[64];
  __shared__ uint32_t pfx[64];
  __shared__ int src[MAXDET];
  int b = blockIdx.x, tid = threadIdx.x;
  int nv = (int)nvalid[b];
  if (tid < 64) {
    uint32_t sw2 = supp[b * 64 + tid];
    int lo = tid * 32;
    uint32_t vm;
    if (nv >= lo + 32) vm = 0xFFFFFFFFu;
    else if (nv <= lo) vm = 0u;
    else vm = (1u << (nv - lo)) - 1u;
    keepw[tid] = (~sw2) & vm;
  }
  for (int s = tid; s < MAXDET; s += 256) src[s] = -1;
  __syncthreads();
  if (tid == 0) {
    uint32_t c = 0;
    for (int w = 0; w < 64; ++w) { pfx[w] = c; c += __popc(keepw[w]); }
  }
  __syncthreads();
  for (int r = tid; r < KTOP; r += 256) {
    int w = r >> 5, t = r & 31;
    uint32_t kw = keepw[w];
    if (!((kw >> t) & 1u)) continue;
    uint32_t rank = pfx[w] + (uint32_t)__popc(kw & ((1u << t) - 1u));
    if (rank < MAXDET) src[rank] = r;
  }
  __syncthreads();
  const float* lg = logits + (size_t)b * NDET * NCLS;
  float* ob = out + (size_t)b * MAXDET * OUTC;
  for (int e = tid; e < MAXDET * OUTC; e += 256) {
    int slot = e / OUTC;
    int c = e - slot * OUTC;
    int r = src[slot];
    float v = 0.0f;
    if (r >= 0) {
      size_t o = (size_t)b * KTOP + r;
      if (c < 4) v = s_box[o * 4 + c];
      else if (c == 4) v = s_score[o];
      else if (c == 5) v = s_clsf[o];
      else v = lg[(size_t)s_n[o] * NCLS + (c - 6)];
    }
    ob[e] = v;
  }
}

extern "C" void kernel_launch(void* const* d_in, const int* in_sizes, int n_in,
                              void* d_out, int out_size, void* d_ws, size_t ws_size,
                              hipStream_t stream) {
  const float* pred = (const float*)d_in[0];
  const float* logits = (const float*)d_in[1];
  float* out = (float*)d_out;

  char* ws = (char*)d_ws;
  size_t off = 0;
  auto alloc = [&](size_t bytes) -> void* {
    void* p = ws + off;
    off += (bytes + 255) & ~(size_t)255;
    return p;
  };
  uint64_t* keys  = (uint64_t*)alloc((size_t)BATCH * NDET * 8);
  uint32_t* sw    = (uint32_t*)alloc((size_t)BATCH * NDET * 4);
  uint32_t* s_n   = (uint32_t*)alloc((size_t)BATCH * KTOP * 4);
  float*    s_sc  = (float*)alloc((size_t)BATCH * KTOP * 4);
  float*    s_cl  = (float*)alloc((size_t)BATCH * KTOP * 4);
  uint32_t* s_cli = (uint32_t*)alloc((size_t)BATCH * KTOP * 4);
  uint32_t* clsbm = (uint32_t*)alloc((size_t)BATCH * BMW * 4);
  float*    s_box = (float*)alloc((size_t)BATCH * KTOP * 16);
  float*    s_ob  = (float*)alloc((size_t)BATCH * KTOP * 16);
  uint32_t* nval  = (uint32_t*)alloc((size_t)BATCH * 4);
  uint32_t* mask  = (uint32_t*)alloc((size_t)BATCH * MROWS * 64 * 4);
  uint32_t* diag  = (uint32_t*)alloc((size_t)BATCH * KTOP * 4);
  uint32_t* suppw = (uint32_t*)alloc((size_t)BATCH * 64 * 4);
  (void)ws_size; (void)in_sizes; (void)n_in;

  int total = BATCH * NDET;
  k_keys<<<(total + 255) / 256, 256, 0, stream>>>(pred, keys, sw);
  k_sel<<<BATCH, 1024, 0, stream>>>(keys, sw, pred, s_n, s_sc, s_cl, s_cli, clsbm, s_box, s_ob, nval);
  k_mask<<<(BATCH * KTOP * 64) / 256, 256, 0, stream>>>(s_ob, s_cli, clsbm, nval, mask, diag);
  k_nms<<<BATCH, 64, 0, stream>>>(mask, diag, nval, suppw);
  k_out<<<BATCH, 256, 0, stream>>>(suppw, nval, s_n, s_sc, s_cl, s_box, logits, out);
}

// Round 9
// 186.498 us; speedup vs baseline: 1.2209x; 1.2209x over previous
//
#include <hip/hip_runtime.h>
#include <stdint.h>

#define BATCH 16
#define NDET 25200
#define NCLS 80
#define PREDC 85
#define KTOP 2048
#define MAXDET 300
#define OUTC 86
#define CONF_THR 0.4f
#define IOU_THR 0.45f
#define MAXWH 4096.0f
#define MROWS (KTOP + 64)       // padded mask rows per batch
#define NBIN 2048
#define NREP 4
#define INVHI 0xBF800000u       // ~mono(-1.0f): score word of invalid rows
#define BMW (NCLS * 64)         // class bitmap words per batch (80 classes x 64)

#define REP32(F) F(0)F(1)F(2)F(3)F(4)F(5)F(6)F(7)F(8)F(9)F(10)F(11)F(12)F(13)F(14)F(15)F(16)F(17)F(18)F(19)F(20)F(21)F(22)F(23)F(24)F(25)F(26)F(27)F(28)F(29)F(30)F(31)

// ---- monotone float<->uint mapping (ascending) ----
__device__ __forceinline__ uint32_t mono_f32(float f) {
  uint32_t u = __float_as_uint(f);
  return (u & 0x80000000u) ? ~u : (u | 0x80000000u);
}
__device__ __forceinline__ float unmono_f32(uint32_t m) {
  uint32_t u = (m & 0x80000000u) ? (m & 0x7FFFFFFFu) : ~m;
  return __uint_as_float(u);
}

// K1: per-candidate score/class -> packed 64-bit key + 32-bit score word.
__global__ void k_keys(const float* __restrict__ pred, uint64_t* __restrict__ keys,
                       uint32_t* __restrict__ sw) {
  int idx = blockIdx.x * blockDim.x + threadIdx.x;
  if (idx >= BATCH * NDET) return;
  int n = idx % NDET;
  const float* p = pred + (size_t)idx * PREDC;
  float obj = p[4];
  float score = -1.0f;
  uint32_t cls = 0;
  if (obj > CONF_THR) {
    float best = -1e30f;
    int bc = 0;
    for (int c = 0; c < NCLS; ++c) {
      float s = __fmul_rn(p[5 + c], obj);   // single-rounded, no contraction
      if (s > best) { best = s; bc = c; }   // strict > : first max (argmax)
    }
    if (best > CONF_THR) { score = best; cls = (uint32_t)bc; }
  }
  uint32_t hi = ~mono_f32(score);
  sw[idx] = hi;
  keys[idx] = ((uint64_t)hi << 32) | (uint64_t)(((uint32_t)n << 7) | cls);
}

// K2: fused radix-select (3x11-bit on score word, exact tie refine) + collect +
// bitonic sort + derive (+ integer class array + per-class rank bitmap).
// One 1024-thread block per batch.
__global__ void __launch_bounds__(1024) k_sel(
    const uint64_t* __restrict__ keys, const uint32_t* __restrict__ sw,
    const float* __restrict__ pred,
    uint32_t* __restrict__ s_n, float* __restrict__ s_score, float* __restrict__ s_clsf,
    uint32_t* __restrict__ s_cli, uint32_t* __restrict__ clsbm,
    float* __restrict__ s_box, float* __restrict__ s_obox, uint32_t* __restrict__ nvalid) {
  __shared__ uint64_t sk[KTOP];            // 16 KB
  __shared__ uint32_t hist[NREP][NBIN];    // 32 KB (reused as class bitmap later)
  __shared__ uint32_t seg[32];
  __shared__ uint32_t sh_digit, sh_cnt, sh_k;
  __shared__ uint32_t ncol, nv;
  int b = blockIdx.x, tid = threadIdx.x, lane = tid & 63;
  int rep = (tid >> 8) & (NREP - 1);
  const uint64_t* kb = keys + (size_t)b * NDET;
  const uint32_t* swb = sw + (size_t)b * NDET;
  const uint4* sw4 = (const uint4*)swb;
  if (tid == 0) { sh_k = KTOP; ncol = 0; nv = 0; }

#define CLEAR_HIST() { __syncthreads(); \
  for (int i = tid; i < NREP * NBIN; i += 1024) ((uint32_t*)hist)[i] = 0; \
  __syncthreads(); }

#define FIND() { __syncthreads(); \
  for (int t = tid; t < NBIN; t += 1024) \
    hist[0][t] = hist[0][t] + hist[1][t] + hist[2][t] + hist[3][t]; \
  __syncthreads(); \
  if (tid < 32) { uint32_t s_ = 0; \
    for (int i_ = 0; i_ < 64; ++i_) s_ += hist[0][tid * 64 + i_]; \
    seg[tid] = s_; } \
  __syncthreads(); \
  if (tid == 0) { uint32_t k_ = sh_k, cum_ = 0; int S_ = 0; \
    for (; S_ < 31; ++S_) { if (cum_ + seg[S_] >= k_) break; cum_ += seg[S_]; } \
    int d_ = S_ * 64; \
    for (;; ++d_) { if (cum_ + hist[0][d_] >= k_) break; cum_ += hist[0][d_]; } \
    sh_digit = (uint32_t)d_; sh_cnt = hist[0][d_]; sh_k = k_ - cum_; } \
  __syncthreads(); }

  // ---- pass 0: bits [31:21] ----
  CLEAR_HIST();
  {
    uint32_t invc = 0;
#define P0(s) { if ((s) == INVHI) ++invc; else atomicAdd(&hist[rep][(s) >> 21], 1u); }
    for (int i = tid; i < NDET / 4; i += 1024) {
      uint4 v = sw4[i];
      P0(v.x) P0(v.y) P0(v.z) P0(v.w)
    }
    if (invc) atomicAdd(&hist[rep][INVHI >> 21], invc);
  }
  FIND();
  uint32_t d0 = sh_digit;

  // ---- pass 1: bits [20:10] among prefix d0 ----
  CLEAR_HIST();
  {
    uint32_t invc = 0;
#define P1(s) { if ((s) == INVHI) ++invc; \
    else if (((s) >> 21) == d0) atomicAdd(&hist[rep][((s) >> 10) & 0x7FFu], 1u); }
    for (int i = tid; i < NDET / 4; i += 1024) {
      uint4 v = sw4[i];
      P1(v.x) P1(v.y) P1(v.z) P1(v.w)
    }
    if (invc && (INVHI >> 21) == d0) atomicAdd(&hist[rep][(INVHI >> 10) & 0x7FFu], invc);
  }
  FIND();
  uint32_t pref21 = (d0 << 11) | sh_digit;

  // ---- pass 2: bits [9:0] among prefix ----
  CLEAR_HIST();
  {
    uint32_t invc = 0;
#define P2(s) { if ((s) == INVHI) ++invc; \
    else if (((s) >> 10) == pref21) atomicAdd(&hist[rep][(s) & 0x3FFu], 1u); }
    for (int i = tid; i < NDET / 4; i += 1024) {
      uint4 v = sw4[i];
      P2(v.x) P2(v.y) P2(v.z) P2(v.w)
    }
    if (invc && (INVHI >> 10) == pref21) atomicAdd(&hist[rep][INVHI & 0x3FFu], invc);
  }
  FIND();
  uint32_t sstar = (pref21 << 10) | sh_digit;
  uint32_t E = sh_cnt, r = sh_k;           // 1 <= r <= E
  uint32_t Lstar = 0xFFFFFFFFu;

  if (r < E) {
    // exact tie refine: r-th smallest low word (22 bits) among sw==sstar.
    CLEAR_HIST();
    for (int n = tid; n < NDET; n += 1024) {
      uint64_t key = kb[n];
      if ((uint32_t)(key >> 32) == sstar)
        atomicAdd(&hist[rep][((uint32_t)key >> 11) & 0x7FFu], 1u);
    }
    FIND();
    uint32_t dr0 = sh_digit;
    CLEAR_HIST();
    for (int n = tid; n < NDET; n += 1024) {
      uint64_t key = kb[n];
      uint32_t low = (uint32_t)key;
      if ((uint32_t)(key >> 32) == sstar && ((low >> 11) & 0x7FFu) == dr0)
        atomicAdd(&hist[rep][low & 0x7FFu], 1u);
    }
    FIND();
    Lstar = (dr0 << 11) | sh_digit;
  }

  // ---- collect exactly KTOP keys ----
  for (int n = tid; n < NDET; n += 1024) {
    uint64_t key = kb[n];
    uint32_t hi = (uint32_t)(key >> 32);
    bool inc = (hi < sstar) || (hi == sstar && (uint32_t)key <= Lstar);
    uint64_t ball = __ballot(inc);
    uint32_t bse = 0;
    if (lane == 0) bse = atomicAdd(&ncol, (uint32_t)__popcll(ball));
    bse = __shfl(bse, 0);
    if (inc) {
      uint32_t pos = bse + (uint32_t)__popcll(ball & ((1ull << lane) - 1ull));
      if (pos < KTOP) sk[pos] = key;
    }
  }

  // ---- bitonic sort ascending ----
  for (int kk = 2; kk <= KTOP; kk <<= 1) {
    for (int j = kk >> 1; j > 0; j >>= 1) {
      __syncthreads();
      for (int i = tid; i < KTOP; i += 1024) {
        int ixj = i ^ j;
        if (ixj > i) {
          uint64_t a = sk[i], c = sk[ixj];
          bool asc = ((i & kk) == 0);
          if ((a > c) == asc) { sk[i] = c; sk[ixj] = a; }
        }
      }
    }
  }
  __syncthreads();

  // ---- class bitmap (reuse hist space; all hist uses are done) ----
  uint32_t* bm = (uint32_t*)hist;          // BMW = 5120 words <= 8192
  for (int i = tid; i < BMW; i += 1024) bm[i] = 0;
  __syncthreads();

  // ---- derive arrays ----
  for (int rr = tid; rr < KTOP; rr += 1024) {
    uint64_t key = sk[rr];
    float score = unmono_f32(~(uint32_t)(key >> 32));
    uint32_t low = (uint32_t)key;
    uint32_t n = low >> 7;
    uint32_t cls = low & 127u;
    uint64_t vball = __ballot(score > 0.0f);
    if (lane == 0) atomicAdd(&nv, (uint32_t)__popcll(vball));
    if (score > 0.0f) atomicOr(&bm[cls * 64 + (rr >> 5)], 1u << (rr & 31));
    const float* p = pred + ((size_t)b * NDET + n) * PREDC;
    float x = p[0], y = p[1], w = p[2], h = p[3];
    float hw = __fmul_rn(w, 0.5f), hh = __fmul_rn(h, 0.5f);
    float x1 = __fsub_rn(x, hw), y1 = __fsub_rn(y, hh);
    float x2 = __fadd_rn(x, hw), y2 = __fadd_rn(y, hh);
    float clsf = (float)cls;
    float off = __fmul_rn(clsf, MAXWH);
    size_t o = (size_t)b * KTOP + rr;
    s_n[o] = n;
    s_score[o] = score;
    s_clsf[o] = clsf;
    s_cli[o] = cls;
    s_box[o * 4 + 0] = x1; s_box[o * 4 + 1] = y1;
    s_box[o * 4 + 2] = x2; s_box[o * 4 + 3] = y2;
    s_obox[o * 4 + 0] = __fadd_rn(x1, off); s_obox[o * 4 + 1] = __fadd_rn(y1, off);
    s_obox[o * 4 + 2] = __fadd_rn(x2, off); s_obox[o * 4 + 3] = __fadd_rn(y2, off);
  }
  __syncthreads();
  for (int i = tid; i < BMW; i += 1024) clsbm[(size_t)b * BMW + i] = bm[i];
  if (tid == 0) nvalid[b] = nv;
}

// K5: suppression bitmask via per-class rank bitmap (cross-class IoU == 0 exactly).
__global__ void k_mask(const float* __restrict__ s_obox, const uint32_t* __restrict__ s_cli,
                       const uint32_t* __restrict__ clsbm, const uint32_t* __restrict__ nvalid,
                       uint32_t* __restrict__ mask, uint32_t* __restrict__ diag) {
  int gid = blockIdx.x * blockDim.x + threadIdx.x; // BATCH*KTOP*64 threads
  int w = gid & 63;
  int i = (gid >> 6) & (KTOP - 1);
  int b = gid >> 17;
  if (i >= (int)nvalid[b]) return;
  int iw = i >> 5, ib = i & 31;
  uint32_t word = 0;
  if (w >= iw) {
    uint32_t ci = s_cli[(size_t)b * KTOP + i];
    uint32_t bmw = clsbm[(size_t)b * BMW + ci * 64 + w];
    uint32_t uptri = (w > iw) ? 0xFFFFFFFFu : ((ib == 31) ? 0u : (0xFFFFFFFFu << (ib + 1)));
    uint32_t mbits = bmw & uptri;
    if (mbits) {
      const float* bi = s_obox + ((size_t)b * KTOP + i) * 4;
      float ix1 = bi[0], iy1 = bi[1], ix2 = bi[2], iy2 = bi[3];
      float iarea = __fmul_rn(__fsub_rn(ix2, ix1), __fsub_rn(iy2, iy1));
      int j0 = w * 32;
      do {
        int t = __ffs(mbits) - 1;
        mbits &= mbits - 1;
        int j = j0 + t;
        const float* bj = s_obox + ((size_t)b * KTOP + j) * 4;
        float jx1 = bj[0], jy1 = bj[1], jx2 = bj[2], jy2 = bj[3];
        float jarea = __fmul_rn(__fsub_rn(jx2, jx1), __fsub_rn(jy2, jy1));
        float ltx = fmaxf(ix1, jx1), lty = fmaxf(iy1, jy1);
        float rbx = fminf(ix2, jx2), rby = fminf(iy2, jy2);
        float wx = fmaxf(__fsub_rn(rbx, ltx), 0.0f);
        float wy = fmaxf(__fsub_rn(rby, lty), 0.0f);
        float inter = __fmul_rn(wx, wy);
        float denom = __fadd_rn(__fsub_rn(__fadd_rn(iarea, jarea), inter), 1e-7f);
        float iou = __fdiv_rn(inter, denom);
        if (iou > IOU_THR) word |= (1u << t);
      } while (mbits);
    }
  }
  mask[((size_t)b * MROWS + i) * 64 + w] = word;
  if (w == iw) diag[(size_t)b * KTOP + i] = word;
}

// K6: sequential greedy pass, one wave per batch; lane l owns removed word l.
__global__ void __launch_bounds__(64, 1) k_nms(
    const uint32_t* __restrict__ mask, const uint32_t* __restrict__ diag,
    const uint32_t* __restrict__ nvalid, uint32_t* __restrict__ supp) {
  __shared__ uint32_t ldsd[KTOP];
  int b = blockIdx.x;
  int lane = threadIdx.x; // 64 threads = 1 wave
  int nv = (int)nvalid[b];
  const uint32_t* mbl = mask + (size_t)b * MROWS * 64 + lane;
  const uint32_t* db = diag + (size_t)b * KTOP;
  for (int i = lane; i < KTOP; i += 64) ldsd[i] = db[i];
  __syncthreads();
  uint32_t removed = 0;
  int ngrp = (nv + 31) >> 5;
  for (int g = 0; g < ngrp; ++g) {
    int base = g * 32;
    int rem = nv - base;
    uint32_t vm = (rem >= 32) ? 0xFFFFFFFFu : ((1u << rem) - 1u);
    const uint32_t* rp = mbl + (size_t)base * 64;
#define DECL_R(d) uint32_t R##d = rp[(size_t)(d) * 64];
    REP32(DECL_R)
#define PIN_R(d) asm volatile("" : "+v"(R##d));
    REP32(PIN_R)
#define DECL_S(d) uint32_t S##d = ldsd[base + d] & ((uint32_t)0 - ((vm >> d) & 1u));
    REP32(DECL_S)
    uint32_t curw = __shfl(removed, g);
    uint32_t cinit = curw;
#define CHAIN(d) { uint32_t m_ = ((curw >> d) & 1u) - 1u; curw |= m_ & S##d; }
    REP32(CHAIN)
    uint32_t am = vm & ~(curw | cinit);
#define APPLY(d) removed |= R##d & ((uint32_t)0 - ((am >> d) & 1u));
    REP32(APPLY)
  }
  supp[b * 64 + lane] = removed;
}

// K7: write the ENTIRE output into a DEVICE staging buffer (fast HBM writes).
// Round-8 lesson: direct kernel stores to d_out ran at 21-27 GB/s (d_out is
// PCIe/host-resident) — 99us. Stage in d_ws, then one SDMA hipMemcpyAsync.
__global__ void __launch_bounds__(1024) k_out(
    const uint32_t* __restrict__ supp, const uint32_t* __restrict__ nvalid,
    const uint32_t* __restrict__ s_n, const float* __restrict__ s_score,
    const float* __restrict__ s_clsf, const float* __restrict__ s_box,
    const float* __restrict__ logits, float* __restrict__ outst) {
  __shared__ uint32_t keepw[64];
  __shared__ uint32_t pfx[64];
  __shared__ int src[MAXDET];
  int b = blockIdx.x, tid = threadIdx.x;
  int nv = (int)nvalid[b];
  if (tid < 64) {
    uint32_t sw2 = supp[b * 64 + tid];
    int lo = tid * 32;
    uint32_t vm;
    if (nv >= lo + 32) vm = 0xFFFFFFFFu;
    else if (nv <= lo) vm = 0u;
    else vm = (1u << (nv - lo)) - 1u;
    keepw[tid] = (~sw2) & vm;
  }
  for (int s = tid; s < MAXDET; s += 1024) src[s] = -1;
  __syncthreads();
  if (tid == 0) {
    uint32_t c = 0;
    for (int w = 0; w < 64; ++w) { pfx[w] = c; c += __popc(keepw[w]); }
  }
  __syncthreads();
  for (int r = tid; r < KTOP; r += 1024) {
    int w = r >> 5, t = r & 31;
    uint32_t kw = keepw[w];
    if (!((kw >> t) & 1u)) continue;
    uint32_t rank = pfx[w] + (uint32_t)__popc(kw & ((1u << t) - 1u));
    if (rank < MAXDET) src[rank] = r;
  }
  __syncthreads();
  const float* lg = logits + (size_t)b * NDET * NCLS;
  float* ob = outst + (size_t)b * MAXDET * OUTC;
  for (int e = tid; e < MAXDET * OUTC; e += 1024) {
    int slot = e / OUTC;
    int c = e - slot * OUTC;
    int r = src[slot];
    float v = 0.0f;
    if (r >= 0) {
      size_t o = (size_t)b * KTOP + r;
      if (c < 4) v = s_box[o * 4 + c];
      else if (c == 4) v = s_score[o];
      else if (c == 5) v = s_clsf[o];
      else v = lg[(size_t)s_n[o] * NCLS + (c - 6)];
    }
    ob[e] = v;
  }
}

extern "C" void kernel_launch(void* const* d_in, const int* in_sizes, int n_in,
                              void* d_out, int out_size, void* d_ws, size_t ws_size,
                              hipStream_t stream) {
  const float* pred = (const float*)d_in[0];
  const float* logits = (const float*)d_in[1];

  char* ws = (char*)d_ws;
  size_t off = 0;
  auto alloc = [&](size_t bytes) -> void* {
    void* p = ws + off;
    off += (bytes + 255) & ~(size_t)255;
    return p;
  };
  uint64_t* keys  = (uint64_t*)alloc((size_t)BATCH * NDET * 8);
  uint32_t* sw    = (uint32_t*)alloc((size_t)BATCH * NDET * 4);
  uint32_t* s_n   = (uint32_t*)alloc((size_t)BATCH * KTOP * 4);
  float*    s_sc  = (float*)alloc((size_t)BATCH * KTOP * 4);
  float*    s_cl  = (float*)alloc((size_t)BATCH * KTOP * 4);
  uint32_t* s_cli = (uint32_t*)alloc((size_t)BATCH * KTOP * 4);
  uint32_t* clsbm = (uint32_t*)alloc((size_t)BATCH * BMW * 4);
  float*    s_box = (float*)alloc((size_t)BATCH * KTOP * 16);
  float*    s_ob  = (float*)alloc((size_t)BATCH * KTOP * 16);
  uint32_t* nval  = (uint32_t*)alloc((size_t)BATCH * 4);
  uint32_t* mask  = (uint32_t*)alloc((size_t)BATCH * MROWS * 64 * 4);
  uint32_t* diag  = (uint32_t*)alloc((size_t)BATCH * KTOP * 4);
  uint32_t* suppw = (uint32_t*)alloc((size_t)BATCH * 64 * 4);
  float*    outst = (float*)alloc((size_t)BATCH * MAXDET * OUTC * 4);
  (void)ws_size; (void)in_sizes; (void)n_in;

  int total = BATCH * NDET;
  k_keys<<<(total + 255) / 256, 256, 0, stream>>>(pred, keys, sw);
  k_sel<<<BATCH, 1024, 0, stream>>>(keys, sw, pred, s_n, s_sc, s_cl, s_cli, clsbm, s_box, s_ob, nval);
  k_mask<<<(BATCH * KTOP * 64) / 256, 256, 0, stream>>>(s_ob, s_cli, clsbm, nval, mask, diag);
  k_nms<<<BATCH, 64, 0, stream>>>(mask, diag, nval, suppw);
  k_out<<<BATCH, 1024, 0, stream>>>(suppw, nval, s_n, s_sc, s_cl, s_box, logits, outst);
  hipMemcpyAsync(d_out, outst, (size_t)out_size * sizeof(float),
                 hipMemcpyDefault, stream);
}